// Round 13
// baseline (5188.984 us; speedup 1.0000x reference)
//
#include <hip/hip_runtime.h>
#include <stdint.h>
#include <math.h>

typedef __attribute__((ext_vector_type(8))) short bf16x8;
typedef __attribute__((ext_vector_type(4))) short s16x4;
typedef __attribute__((ext_vector_type(4))) float f32x4;
typedef unsigned short u16;

// raw barrier: LDS drain only; global (vmcnt) prefetches stay in flight
#define SBAR() asm volatile("s_waitcnt lgkmcnt(0)\ns_barrier" ::: "memory")

__device__ __forceinline__ short f2bf(float f){
  union { float f; uint32_t u; } v; v.f = f;
  uint32_t r = v.u + 0x7FFFu + ((v.u >> 16) & 1u);
  return (short)(r >> 16);
}
__device__ __forceinline__ float bf2f(u16 b){
  union { uint32_t u; float f; } v; v.u = ((uint32_t)b) << 16; return v.f;
}
__device__ __forceinline__ bool getb(const void* p, int i, int flag){
  if (flag) return ((const unsigned char*)p)[i] != 0;
  return ((const int*)p)[i] != 0;
}
// XOR-swizzled offsets (u16 elements), row widths 256/128/64
__device__ __forceinline__ int xoff(int row, int col){
  int g = (col >> 3) ^ (row & 7);
  return row * 256 + (g << 3) + (col & 7);
}
__device__ __forceinline__ int swz128(int row, int col){
  return row * 128 + (((col >> 3) ^ (row & 7)) << 3) + (col & 7);
}
__device__ __forceinline__ int swz64(int row, int col){
  return row * 64 + (((col >> 3) ^ (row & 7)) << 3) + (col & 7);
}

__global__ void detect_bool_k(const void* pad, int* flag){
  const unsigned char* b = (const unsigned char*)pad;
  int f = 0;
  for (int i = 1; i < 64; ++i) if (i & 3) f |= (b[i] != 0) ? 1 : 0;
  *flag = f;
}

// Pack f32 W [mats][K][N] into MFMA-fragment-linear bf16
__global__ void pack_k(const float* __restrict__ src, u16* __restrict__ dst, int K, int N){
  long idx = (long)blockIdx.x * blockDim.x + threadIdx.x;
  int j = (int)(idx & 7);
  int lane = (int)((idx >> 3) & 63);
  long t = idx >> 9;
  int KT = K >> 5;
  int kt = (int)(t % KT);
  long t2 = t / KT;
  int NT = N >> 4;
  int nt = (int)(t2 % NT);
  int m = (int)(t2 / NT);
  int li = lane & 15, lg = lane >> 4;
  int k = 32*kt + 8*lg + j, n = 16*nt + li;
  dst[idx] = (u16)f2bf(src[((long)m * K + k) * N + n]);
}

__global__ void emb2bf_k(const float* __restrict__ src, u16* __restrict__ dst){
  long i = (long)blockIdx.x * blockDim.x + threadIdx.x;
  dst[i] = (u16)f2bf(src[i]);
}

__global__ void pos_init_k(const int* __restrict__ pos, float* __restrict__ reprs){
  int n = blockIdx.x, d = threadIdx.x;
  double p = (double)pos[n];
  int i = (d < 128) ? d : d - 128;
  double ang = p / pow(500.0, (2.0 * (double)i) / 256.0);
  reprs[n * 256 + d] = (d < 128) ? (float)sin(ang) : (float)cos(ang);
}

__global__ void zero_counts_k(int* c){ if (threadIdx.x < 4) c[threadIdx.x] = 0; }

__global__ void compact_k(const int* __restrict__ sortv, int* __restrict__ lists,
                          int* __restrict__ counts){
  int t = blockIdx.x * 256 + threadIdx.x;
  int r = sortv[t];
  int pos = atomicAdd(&counts[r], 1);
  lists[r * 2048 + pos] = t;
}

__global__ void update_k(const int* __restrict__ sortv, const float* __restrict__ encCLS,
                         float* __restrict__ reprs, int rank){
  int t = blockIdx.x;
  if (sortv[t] != rank) return;
  reprs[t * 256 + threadIdx.x] += encCLS[t * 256 + threadIdx.x];
}

__global__ void writeout_k(const float* __restrict__ reprs, float* __restrict__ out){
  int i = blockIdx.x * 256 + threadIdx.x;
  out[i] = reprs[i];
}

// One block = one term, 4 waves (256 threads), all 4 layers fused.
// LDS exactly 65536 B -> 2 INDEPENDENT blocks/CU (decoupled barriers) at the
// proven 128-VGPR + ~128-AGPR budget (R6 structure, no spill).
// P overlays the Q region (wave-private stripe; aq preloaded -> zero extra barriers).
__global__ __launch_bounds__(256, 2)
void encode_k(const int* __restrict__ tokens, const void* __restrict__ pad,
              const void* __restrict__ refm, const int* __restrict__ boolflag,
              const float* __restrict__ storage, const u16* __restrict__ embB,
              const u16* __restrict__ WqF, const u16* __restrict__ WkF,
              const u16* __restrict__ WvF, const u16* __restrict__ WoF,
              const u16* __restrict__ W1F, const float* __restrict__ b1,
              const u16* __restrict__ W2F, const float* __restrict__ b2,
              const float* __restrict__ ln1s, const float* __restrict__ ln1b,
              const float* __restrict__ ln2s, const float* __restrict__ ln2b,
              const int* __restrict__ list, const int* __restrict__ cnt,
              float* __restrict__ outCLS)
{
  int term;
  if (list){
    if ((int)blockIdx.x >= *cnt) return;
    term = list[blockIdx.x];
  } else {
    term = blockIdx.x;
  }
  const int flag = *boolflag;

  __shared__ u16 sXb[64 * 256];     // 32768 B bf16 X (swz256)
  __shared__ u16 sPoolA[64 * 128];  // 16384 B: Q(cols 0-63)|K(64-127) swz128; P overlays Q; sH0
  __shared__ u16 sPoolB[64 * 128];  // 16384 B: sVT(8K)+sO(8K) swz64 | sH1 swz128; sStat/sTok/sRef overlays

  u16* sQK = sPoolA;
  u16* sVT = sPoolB;
  u16* sO  = sPoolB + 64 * 64;
  u16* sH0 = sPoolA;
  u16* sH1 = sPoolB;
  float (*sStat)[8] = (float(*)[8])sPoolB;  // overlay: sVT region (LN1) / sH1 region (LN2, extra SBAR)
  int* sTok = (int*)sPoolB;                 // overlay, dead after X build
  int* sRef = sTok + 192;

  const int tid = threadIdx.x;
  const int w = tid >> 6, lane = tid & 63, lg = lane >> 4, li = lane & 15;
  const f32x4 zero4 = {0.f, 0.f, 0.f, 0.f};

  if (tid < 192) sTok[tid] = tokens[term * 192 + tid];
  if (tid < 64) sRef[tid] = getb(refm, term * 64 + tid, flag) ? 1 : 0;
  // pad mask in registers: mk4[ct] covers key 16ct+li
  float mk4[4];
  #pragma unroll
  for (int ct = 0; ct < 4; ++ct)
    mk4[ct] = getb(pad, term * 64 + 16*ct + li, flag) ? 0.f : -1e9f;
  SBAR();

  // build X (256 threads, 64 rows)
  #pragma unroll 4
  for (int s = 0; s < 64; ++s){
    float v;
    if (sRef[s]){
      v = storage[sTok[3*s + 1] * 256 + tid];
    } else {
      v = bf2f(embB[sTok[3*s + 0] * 256 + tid])
        + bf2f(embB[(2048 + sTok[3*s + 1]) * 256 + tid])
        + bf2f(embB[(4096 + sTok[3*s + 2]) * 256 + tid]);
    }
    sXb[xoff(s, tid)] = (u16)f2bf(v);
  }
  SBAR();   // X visible; sTok/sRef retired (PoolB free)

  // X residual in registers at this thread's C-fragment positions
  float xres[4][4][4];
  #pragma unroll
  for (int rt = 0; rt < 4; ++rt)
    #pragma unroll
    for (int ctl = 0; ctl < 4; ++ctl)
      #pragma unroll
      for (int r = 0; r < 4; ++r)
        xres[rt][ctl][r] = bf2f(sXb[xoff(16*rt + 4*lg + r, 64*w + 16*ctl + li)]);

  auto ldA = [&](int rt, int kk) -> bf16x8 {
    return *(const bf16x8*)&sXb[(16*rt + li) * 256 + (((4*kk + lg) ^ (li & 7)) << 3)];
  };

  for (int l = 0; l < 4; ++l){
    // ================= attention (incremental Wo accumulate) =================
    f32x4 ga[4][4];
    #pragma unroll
    for (int rt = 0; rt < 4; ++rt)
      #pragma unroll
      for (int c = 0; c < 4; ++c) ga[rt][c] = zero4;

    for (int hp = 0; hp < 4; ++hp){
      // ---- QKV GEMM: wave w owns local cols [48w,48w+48) of Q(64)|K(64)|V(64)
      f32x4 acc[4][3];
      #pragma unroll
      for (int rt = 0; rt < 4; ++rt)
        #pragma unroll
        for (int c = 0; c < 3; ++c) acc[rt][c] = zero4;

      const u16* bF[3];
      #pragma unroll
      for (int ctl = 0; ctl < 3; ++ctl){
        int c = 48 * w + 16 * ctl;
        int mm = c >> 6;                       // 0:Q 1:K 2:V
        int nt = hp * 4 + ((c & 63) >> 4);
        const u16* Wt = (mm == 0) ? WqF : ((mm == 1) ? WkF : WvF);
        bF[ctl] = Wt + (((size_t)(l * 16 + nt) * 8) * 64 + lane) * 8;
      }
      bf16x8 bq[8][3];
      #pragma unroll
      for (int kt = 0; kt < 8; ++kt)
        #pragma unroll
        for (int ctl = 0; ctl < 3; ++ctl)
          bq[kt][ctl] = *(const bf16x8*)(bF[ctl] + (size_t)kt * 512);
      #pragma unroll
      for (int kt = 0; kt < 8; ++kt){
        bf16x8 a[4];
        #pragma unroll
        for (int rt = 0; rt < 4; ++rt) a[rt] = ldA(rt, kt);
        #pragma unroll
        for (int ctl = 0; ctl < 3; ++ctl)
          #pragma unroll
          for (int rt = 0; rt < 4; ++rt)
            acc[rt][ctl] = __builtin_amdgcn_mfma_f32_16x16x32_bf16(a[rt], bq[kt][ctl], acc[rt][ctl], 0, 0, 0);
      }
      // ---- scatter Q|K (swz128) and V^T (swz64)
      #pragma unroll
      for (int rt = 0; rt < 4; ++rt)
        #pragma unroll
        for (int ctl = 0; ctl < 3; ++ctl){
          int c = 48*w + 16*ctl;
          if (c < 128){
            #pragma unroll
            for (int r = 0; r < 4; ++r)
              sQK[swz128(16*rt + 4*lg + r, c + li)] = (u16)f2bf(acc[rt][ctl][r]);
          } else {
            s16x4 pk;
            #pragma unroll
            for (int r = 0; r < 4; ++r) pk[r] = f2bf(acc[rt][ctl][r]);
            *(s16x4*)&sVT[swz64(c + li - 128, 16*rt + 4*lg)] = pk;
          }
        }
      // prefetch Wo B-fragments (global; survive the raw barrier)
      bf16x8 woB[2][4];
      #pragma unroll
      for (int kt2 = 0; kt2 < 2; ++kt2)
        #pragma unroll
        for (int ctl = 0; ctl < 4; ++ctl)
          woB[kt2][ctl] = *(const bf16x8*)(WoF +
              (((size_t)(l*16 + 4*w + ctl) * 8 + 2*hp + kt2) * 64 + lane) * 8);
      SBAR();   // scatter visible

      // ---- attention: wave w = q-stripe rows [16w,16w+16), both heads
      // preload Q fragments for BOTH heads; then the Q stripe becomes this wave's P arena
      bf16x8 aq0 = *(const bf16x8*)&sQK[swz128(16*w + li, 0  + 8*lg)];
      bf16x8 aq1 = *(const bf16x8*)&sQK[swz128(16*w + li, 32 + 8*lg)];
      #pragma unroll
      for (int hh = 0; hh < 2; ++hh){
        bf16x8 aq = hh ? aq1 : aq0;
        f32x4 sc[4];
        #pragma unroll
        for (int ct = 0; ct < 4; ++ct){
          bf16x8 bk = *(const bf16x8*)&sQK[swz128(16*ct + li, 64 + 32*hh + 8*lg)];
          sc[ct] = __builtin_amdgcn_mfma_f32_16x16x32_bf16(aq, bk, zero4, 0, 0, 0);
        }
        float sv[4][4];
        #pragma unroll
        for (int ct = 0; ct < 4; ++ct)
          #pragma unroll
          for (int r = 0; r < 4; ++r)
            sv[ct][r] = sc[ct][r] * 0.17677669529663687f + mk4[ct];
        #pragma unroll
        for (int r = 0; r < 4; ++r){
          float m = fmaxf(fmaxf(sv[0][r], sv[1][r]), fmaxf(sv[2][r], sv[3][r]));
          #pragma unroll
          for (int o = 1; o < 16; o <<= 1) m = fmaxf(m, __shfl_xor(m, o, 64));
          float s0 = 0.f;
          #pragma unroll
          for (int ct = 0; ct < 4; ++ct){ float e = __expf(sv[ct][r] - m); sv[ct][r] = e; s0 += e; }
          #pragma unroll
          for (int o = 1; o < 16; o <<= 1) s0 += __shfl_xor(s0, o, 64);
          float inv = 1.f / s0;
          #pragma unroll
          for (int ct = 0; ct < 4; ++ct) sv[ct][r] *= inv;
        }
        // P stripe into own Q rows (wave-private; same-wave LDS order: aq already read)
        #pragma unroll
        for (int ct = 0; ct < 4; ++ct)
          #pragma unroll
          for (int r = 0; r < 4; ++r)
            sQK[swz128(16*w + 4*lg + r, 16*ct + li)] = (u16)f2bf(sv[ct][r]);
        // PV: O = P @ V  (V^T b128 reads)
        f32x4 oa[2] = {zero4, zero4};
        #pragma unroll
        for (int kt = 0; kt < 2; ++kt){
          bf16x8 ap = *(const bf16x8*)&sQK[swz128(16*w + li, 32*kt + 8*lg)];
          #pragma unroll
          for (int ct = 0; ct < 2; ++ct){
            bf16x8 bv = *(const bf16x8*)&sVT[swz64(32*hh + 16*ct + li, 32*kt + 8*lg)];
            oa[ct] = __builtin_amdgcn_mfma_f32_16x16x32_bf16(ap, bv, oa[ct], 0, 0, 0);
          }
        }
        #pragma unroll
        for (int ct = 0; ct < 2; ++ct)
          #pragma unroll
          for (int r = 0; r < 4; ++r)
            sO[swz64(16*w + 4*lg + r, 32*hh + 16*ct + li)] = (u16)f2bf(oa[ct][r]);
      }
      SBAR();   // sO complete; P dead (guards next hp's scatter into PoolA)
      // partial Wo: ga += O[:, 64hp:64hp+64) @ Wo[64hp:64hp+64, :]
      #pragma unroll
      for (int kt2 = 0; kt2 < 2; ++kt2){
        bf16x8 a[4];
        #pragma unroll
        for (int rt = 0; rt < 4; ++rt)
          a[rt] = *(const bf16x8*)&sO[swz64(16*rt + li, 32*kt2 + 8*lg)];
        #pragma unroll
        for (int ctl = 0; ctl < 4; ++ctl)
          #pragma unroll
          for (int rt = 0; rt < 4; ++rt)
            ga[rt][ctl] = __builtin_amdgcn_mfma_f32_16x16x32_bf16(a[rt], woB[kt2][ctl], ga[rt][ctl], 0, 0, 0);
      }
    } // hp

    // ================= residual + LN1 (sStat overlays dead sVT region) =================
    {
      float g4[4], bb4[4];
      #pragma unroll
      for (int ctl = 0; ctl < 4; ++ctl){
        int col = 64*w + 16*ctl + li;
        g4[ctl] = ln1s[l*256 + col]; bb4[ctl] = ln1b[l*256 + col];
      }
      float s1v[4][4], s2v[4][4];
      #pragma unroll
      for (int rt = 0; rt < 4; ++rt)
        #pragma unroll
        for (int r = 0; r < 4; ++r){
          float t1 = 0.f, t2 = 0.f;
          #pragma unroll
          for (int ctl = 0; ctl < 4; ++ctl){
            float y = ga[rt][ctl][r] + xres[rt][ctl][r];
            ga[rt][ctl][r] = y; t1 += y; t2 += y * y;
          }
          #pragma unroll
          for (int o = 1; o < 16; o <<= 1){ t1 += __shfl_xor(t1, o, 64); t2 += __shfl_xor(t2, o, 64); }
          s1v[rt][r] = t1; s2v[rt][r] = t2;
        }
      if (li == 0){
        #pragma unroll
        for (int rt = 0; rt < 4; ++rt)
          #pragma unroll
          for (int r = 0; r < 4; ++r){
            sStat[16*rt + 4*lg + r][w] = s1v[rt][r];
            sStat[16*rt + 4*lg + r][4 + w] = s2v[rt][r];
          }
      }
      SBAR();
      #pragma unroll
      for (int rt = 0; rt < 4; ++rt)
        #pragma unroll
        for (int r = 0; r < 4; ++r){
          int row = 16*rt + 4*lg + r;
          float su = sStat[row][0] + sStat[row][1] + sStat[row][2] + sStat[row][3];
          float sq = sStat[row][4] + sStat[row][5] + sStat[row][6] + sStat[row][7];
          float mean = su * (1.f / 256.f);
          float var = sq * (1.f / 256.f) - mean * mean;
          float rs = rsqrtf(var + 1e-5f);
          #pragma unroll
          for (int ctl = 0; ctl < 4; ++ctl){
            int col = 64*w + 16*ctl + li;
            float nv = (ga[rt][ctl][r] - mean) * rs * g4[ctl] + bb4[ctl];
            xres[rt][ctl][r] = nv;
            sXb[xoff(row, col)] = (u16)f2bf(nv);
          }
        }
      SBAR();
    }

    // ================= FFN: dbuf hidden (sH0=PoolA, sH1=PoolB), pipelined W loads ===========
    {
      float b1v[8][2];
      #pragma unroll
      for (int ch = 0; ch < 8; ++ch)
        #pragma unroll
        for (int ctl = 0; ctl < 2; ++ctl)
          b1v[ch][ctl] = b1[l*1024 + 128*ch + 32*w + 16*ctl + li];

      bf16x8 w1f[2][8];
      auto loadW1 = [&](int ch){
        #pragma unroll
        for (int ctl = 0; ctl < 2; ++ctl){
          const u16* p0 = W1F + (((size_t)(l*64 + 8*ch + 2*w + ctl) * 8) * 64 + lane) * 8;
          #pragma unroll
          for (int kt = 0; kt < 8; ++kt)
            w1f[ctl][kt] = *(const bf16x8*)(p0 + (size_t)kt * 512);
        }
      };
      auto mfma1 = [&](f32x4 (*h)[2]){
        #pragma unroll
        for (int rt = 0; rt < 4; ++rt){ h[rt][0] = zero4; h[rt][1] = zero4; }
        #pragma unroll
        for (int kt = 0; kt < 8; ++kt){
          bf16x8 a[4];
          #pragma unroll
          for (int rt = 0; rt < 4; ++rt) a[rt] = ldA(rt, kt);
          #pragma unroll
          for (int ctl = 0; ctl < 2; ++ctl)
            #pragma unroll
            for (int rt = 0; rt < 4; ++rt)
              h[rt][ctl] = __builtin_amdgcn_mfma_f32_16x16x32_bf16(a[rt], w1f[ctl][kt], h[rt][ctl], 0, 0, 0);
        }
      };

      f32x4 fa[4][4];
      #pragma unroll
      for (int rt = 0; rt < 4; ++rt)
        #pragma unroll
        for (int c = 0; c < 4; ++c) fa[rt][c] = zero4;

      f32x4 haA[4][2], haB[4][2];
      loadW1(0);
      mfma1(haA);

      #pragma unroll
      for (int ch = 0; ch < 8; ++ch){
        f32x4 (*cur)[2] = (ch & 1) ? haB : haA;
        f32x4 (*nxt)[2] = (ch & 1) ? haA : haB;
        u16* sHc = (ch & 1) ? sH1 : sH0;
        #pragma unroll
        for (int rt = 0; rt < 4; ++rt)
          #pragma unroll
          for (int ctl = 0; ctl < 2; ++ctl)
            #pragma unroll
            for (int r = 0; r < 4; ++r){
              float v = cur[rt][ctl][r] + b1v[ch][ctl];
              sHc[swz128(16*rt + 4*lg + r, 32*w + 16*ctl + li)] = (u16)f2bf(fmaxf(v, 0.f));
            }
        // pre-barrier issue of W2(ch) first half; survives the raw barrier
        bf16x8 w2a[2][4];
        #pragma unroll
        for (int kt = 0; kt < 2; ++kt)
          #pragma unroll
          for (int ctl = 0; ctl < 4; ++ctl)
            w2a[kt][ctl] = *(const bf16x8*)(W2F +
                (((size_t)(l*16 + 4*w + ctl) * 32 + 4*ch + kt) * 64 + lane) * 8);
        SBAR();    // hidden chunk visible
        if (ch < 7) loadW1(ch + 1);
        // GEMM2(ch) first half
        #pragma unroll
        for (int kt = 0; kt < 2; ++kt){
          bf16x8 a[4];
          #pragma unroll
          for (int rt = 0; rt < 4; ++rt)
            a[rt] = *(const bf16x8*)&sHc[swz128(16*rt + li, 32*kt + 8*lg)];
          #pragma unroll
          for (int ctl = 0; ctl < 4; ++ctl)
            #pragma unroll
            for (int rt = 0; rt < 4; ++rt)
              fa[rt][ctl] = __builtin_amdgcn_mfma_f32_16x16x32_bf16(a[rt], w2a[kt][ctl], fa[rt][ctl], 0, 0, 0);
        }
        // GEMM2(ch) second half
        #pragma unroll
        for (int kt = 2; kt < 4; ++kt){
          bf16x8 br[4];
          #pragma unroll
          for (int ctl = 0; ctl < 4; ++ctl)
            br[ctl] = *(const bf16x8*)(W2F +
                (((size_t)(l*16 + 4*w + ctl) * 32 + 4*ch + kt) * 64 + lane) * 8);
          bf16x8 a[4];
          #pragma unroll
          for (int rt = 0; rt < 4; ++rt)
            a[rt] = *(const bf16x8*)&sHc[swz128(16*rt + li, 32*kt + 8*lg)];
          #pragma unroll
          for (int ctl = 0; ctl < 4; ++ctl)
            #pragma unroll
            for (int rt = 0; rt < 4; ++rt)
              fa[rt][ctl] = __builtin_amdgcn_mfma_f32_16x16x32_bf16(a[rt], br[ctl], fa[rt][ctl], 0, 0, 0);
        }
        if (ch < 7) mfma1(nxt);
      }

      // ---- residual + bias + LN2 (sStat overlays sH1=PoolB: drain GEMM2 readers first)
      SBAR();
      float g4[4], bb4[4], b2v[4];
      #pragma unroll
      for (int ctl = 0; ctl < 4; ++ctl){
        int col = 64*w + 16*ctl + li;
        g4[ctl] = ln2s[l*256 + col]; bb4[ctl] = ln2b[l*256 + col]; b2v[ctl] = b2[l*256 + col];
      }
      float s1v[4][4], s2v[4][4];
      #pragma unroll
      for (int rt = 0; rt < 4; ++rt)
        #pragma unroll
        for (int r = 0; r < 4; ++r){
          float t1 = 0.f, t2 = 0.f;
          #pragma unroll
          for (int ctl = 0; ctl < 4; ++ctl){
            float y = fa[rt][ctl][r] + xres[rt][ctl][r] + b2v[ctl];
            fa[rt][ctl][r] = y; t1 += y; t2 += y * y;
          }
          #pragma unroll
          for (int o = 1; o < 16; o <<= 1){ t1 += __shfl_xor(t1, o, 64); t2 += __shfl_xor(t2, o, 64); }
          s1v[rt][r] = t1; s2v[rt][r] = t2;
        }
      if (li == 0){
        #pragma unroll
        for (int rt = 0; rt < 4; ++rt)
          #pragma unroll
          for (int r = 0; r < 4; ++r){
            sStat[16*rt + 4*lg + r][w] = s1v[rt][r];
            sStat[16*rt + 4*lg + r][4 + w] = s2v[rt][r];
          }
      }
      SBAR();
      #pragma unroll
      for (int rt = 0; rt < 4; ++rt)
        #pragma unroll
        for (int r = 0; r < 4; ++r){
          int row = 16*rt + 4*lg + r;
          float su = sStat[row][0] + sStat[row][1] + sStat[row][2] + sStat[row][3];
          float sq = sStat[row][4] + sStat[row][5] + sStat[row][6] + sStat[row][7];
          float mean = su * (1.f / 256.f);
          float var = sq * (1.f / 256.f) - mean * mean;
          float rs = rsqrtf(var + 1e-5f);
          #pragma unroll
          for (int ctl = 0; ctl < 4; ++ctl){
            int col = 64*w + 16*ctl + li;
            float nv = (fa[rt][ctl][r] - mean) * rs * g4[ctl] + bb4[ctl];
            xres[rt][ctl][r] = nv;
            sXb[xoff(row, col)] = (u16)f2bf(nv);
            if (l == 3 && outCLS && row == 0) outCLS[term * 256 + col] = nv;
          }
        }
      SBAR();
    }
  }
}

extern "C" void kernel_launch(void* const* d_in, const int* in_sizes, int n_in,
                              void* d_out, int out_size, void* d_ws, size_t ws_size,
                              hipStream_t stream)
{
  (void)in_sizes; (void)n_in; (void)out_size; (void)ws_size;
  const int* tokens_scope = (const int*)d_in[0];
  const int* tokens_hole  = (const int*)d_in[1];
  const void* pad_scope = d_in[2];
  const void* pad_hole  = d_in[3];
  const void* ref_scope = d_in[4];
  const void* ref_hole  = d_in[5];
  const int* scope_sort = (const int*)d_in[6];
  const int* scope_pos  = (const int*)d_in[7];
  const float* emb  = (const float*)d_in[8];
  const float* Wq   = (const float*)d_in[9];
  const float* Wk   = (const float*)d_in[10];
  const float* Wv   = (const float*)d_in[11];
  const float* Wo   = (const float*)d_in[12];
  const float* ln1s = (const float*)d_in[13];
  const float* ln1b = (const float*)d_in[14];
  const float* W1   = (const float*)d_in[15];
  const float* b1   = (const float*)d_in[16];
  const float* W2   = (const float*)d_in[17];
  const float* b2   = (const float*)d_in[18];
  const float* ln2s = (const float*)d_in[19];
  const float* ln2b = (const float*)d_in[20];

  char* p = (char*)d_ws;
  float* reprs  = (float*)p; p += (size_t)2048*256*4;
  float* encCLS = (float*)p; p += (size_t)2048*256*4;
  u16* WqF = (u16*)p; p += (size_t)4*256*256*2;
  u16* WkF = (u16*)p; p += (size_t)4*256*256*2;
  u16* WvF = (u16*)p; p += (size_t)4*256*256*2;
  u16* WoF = (u16*)p; p += (size_t)4*256*256*2;
  u16* W1F = (u16*)p; p += (size_t)4*256*1024*2;
  u16* W2F = (u16*)p; p += (size_t)4*256*1024*2;
  u16* embB = (u16*)p; p += (size_t)3*2048*256*2;
  int* lists = (int*)p; p += (size_t)4*2048*4;
  int* counts = (int*)p; p += 64;
  int* flag = (int*)p; p += 16;

  hipLaunchKernelGGL(detect_bool_k, dim3(1), dim3(1), 0, stream, pad_scope, flag);
  hipLaunchKernelGGL(emb2bf_k, dim3(6144), dim3(256), 0, stream, emb, embB);
  hipLaunchKernelGGL(pack_k, dim3(1024), dim3(256), 0, stream, Wq, WqF, 256, 256);
  hipLaunchKernelGGL(pack_k, dim3(1024), dim3(256), 0, stream, Wk, WkF, 256, 256);
  hipLaunchKernelGGL(pack_k, dim3(1024), dim3(256), 0, stream, Wv, WvF, 256, 256);
  hipLaunchKernelGGL(pack_k, dim3(1024), dim3(256), 0, stream, Wo, WoF, 256, 256);
  hipLaunchKernelGGL(pack_k, dim3(4096), dim3(256), 0, stream, W1, W1F, 256, 1024);
  hipLaunchKernelGGL(pack_k, dim3(4096), dim3(256), 0, stream, W2, W2F, 1024, 256);
  hipLaunchKernelGGL(pos_init_k, dim3(2048), dim3(256), 0, stream, scope_pos, reprs);
  hipLaunchKernelGGL(zero_counts_k, dim3(1), dim3(64), 0, stream, counts);
  hipLaunchKernelGGL(compact_k, dim3(8), dim3(256), 0, stream, scope_sort, lists, counts);

  for (int r = 0; r < 4; ++r){
    hipLaunchKernelGGL(encode_k, dim3(2048), dim3(256), 0, stream,
      tokens_scope, pad_scope, ref_scope, flag, reprs, embB,
      WqF, WkF, WvF, WoF, W1F, b1, W2F, b2, ln1s, ln1b, ln2s, ln2b,
      lists + (size_t)r*2048, counts + r, encCLS);
    hipLaunchKernelGGL(update_k, dim3(2048), dim3(256), 0, stream, scope_sort, encCLS, reprs, r);
  }
  hipLaunchKernelGGL(encode_k, dim3(512), dim3(256), 0, stream,
      tokens_hole, pad_hole, ref_hole, flag, reprs, embB,
      WqF, WkF, WvF, WoF, W1F, b1, W2F, b2, ln1s, ln1b, ln2s, ln2b,
      (const int*)nullptr, (const int*)nullptr, (float*)d_out + (size_t)2048*256);
  hipLaunchKernelGGL(writeout_k, dim3(2048), dim3(256), 0, stream, reprs, (float*)d_out);
}

// Round 14
// 2774.745 us; speedup vs baseline: 1.8701x; 1.8701x over previous
//
#include <hip/hip_runtime.h>
#include <stdint.h>
#include <math.h>

typedef __attribute__((ext_vector_type(8))) short bf16x8;
typedef __attribute__((ext_vector_type(4))) short s16x4;
typedef __attribute__((ext_vector_type(4))) float f32x4;
typedef unsigned short u16;

// raw barrier: LDS drain only; global (vmcnt) prefetches stay in flight
#define SBAR() asm volatile("s_waitcnt lgkmcnt(0)\ns_barrier" ::: "memory")

__device__ __forceinline__ short f2bf(float f){
  union { float f; uint32_t u; } v; v.f = f;
  uint32_t r = v.u + 0x7FFFu + ((v.u >> 16) & 1u);
  return (short)(r >> 16);
}
__device__ __forceinline__ float bf2f(u16 b){
  union { uint32_t u; float f; } v; v.u = ((uint32_t)b) << 16; return v.f;
}
__device__ __forceinline__ bool getb(const void* p, int i, int flag){
  if (flag) return ((const unsigned char*)p)[i] != 0;
  return ((const int*)p)[i] != 0;
}
// XOR-swizzled offset into the bf16 X buffer [64 rows][256 cols]
__device__ __forceinline__ int xoff(int row, int col){
  int g = (col >> 3) ^ (row & 7);
  return row * 256 + (g << 3) + (col & 7);
}

__global__ void detect_bool_k(const void* pad, int* flag, int* counts){
  if (threadIdx.x < 4) counts[threadIdx.x] = 0;
  if (threadIdx.x == 0){
    const unsigned char* b = (const unsigned char*)pad;
    int f = 0;
    for (int i = 1; i < 64; ++i) if (i & 3) f |= (b[i] != 0) ? 1 : 0;
    *flag = f;
  }
}

// ONE prologue kernel:
//   blocks [0,6144): emb f32 -> bf16 straight convert
//   blocks [6144,18432): pack six W tensors into MFMA-fragment-linear bf16
//     dst[(((m*(N/16)+nt)*(K/32)+kt)*64 + lane)*8 + j] = W[m][32kt+8lg+j][16nt+li]
//   blocks [18432,20480): sinusoidal pos-enc init of reprs
__global__ void prep_k(const float* __restrict__ emb, u16* __restrict__ embB,
                       const float* __restrict__ Wq, const float* __restrict__ Wk,
                       const float* __restrict__ Wv, const float* __restrict__ Wo,
                       const float* __restrict__ W1, const float* __restrict__ W2,
                       u16* __restrict__ WqF, u16* __restrict__ WkF,
                       u16* __restrict__ WvF, u16* __restrict__ WoF,
                       u16* __restrict__ W1F, u16* __restrict__ W2F,
                       const int* __restrict__ pos, float* __restrict__ reprs){
  int b = blockIdx.x;
  if (b < 6144){
    long i = (long)b * 256 + threadIdx.x;
    embB[i] = (u16)f2bf(emb[i]);
    return;
  }
  if (b >= 18432){
    int n = b - 18432, d = threadIdx.x;
    double p = (double)pos[n];
    int i = (d < 128) ? d : d - 128;
    double ang = p / pow(500.0, (2.0 * (double)i) / 256.0);
    reprs[n * 256 + d] = (d < 128) ? (float)sin(ang) : (float)cos(ang);
    return;
  }
  b -= 6144;
  const float* src; u16* dst; int K, N;
  if (b < 4096){
    int t = b >> 10; b &= 1023;
    if (t == 0){ src = Wq; dst = WqF; }
    else if (t == 1){ src = Wk; dst = WkF; }
    else if (t == 2){ src = Wv; dst = WvF; }
    else { src = Wo; dst = WoF; }
    K = 256; N = 256;
  } else if (b < 8192){ src = W1; dst = W1F; K = 256; N = 1024; b -= 4096; }
  else { src = W2; dst = W2F; K = 1024; N = 256; b -= 8192; }
  long idx = (long)b * 256 + threadIdx.x;
  int j = (int)(idx & 7);
  int lane = (int)((idx >> 3) & 63);
  long t2a = idx >> 9;
  int KT = K >> 5;
  int kt = (int)(t2a % KT);
  long t2 = t2a / KT;
  int NT = N >> 4;
  int nt = (int)(t2 % NT);
  int m = (int)(t2 / NT);
  int li = lane & 15, lg = lane >> 4;
  int k = 32*kt + 8*lg + j, n = 16*nt + li;
  dst[idx] = (u16)f2bf(src[((long)m * K + k) * N + n]);
}

__global__ void compact_k(const int* __restrict__ sortv, int* __restrict__ lists,
                          int* __restrict__ counts){
  int t = blockIdx.x * 256 + threadIdx.x;
  int r = sortv[t];
  int pos = atomicAdd(&counts[r], 1);
  lists[r * 2048 + pos] = t;
}

__global__ void update_k(const int* __restrict__ sortv, const float* __restrict__ encCLS,
                         float* __restrict__ reprs, int rank){
  int t = blockIdx.x;
  if (sortv[t] != rank) return;
  reprs[t * 256 + threadIdx.x] += encCLS[t * 256 + threadIdx.x];
}

__global__ void writeout_k(const float* __restrict__ reprs, float* __restrict__ out){
  int i = blockIdx.x * 256 + threadIdx.x;
  out[i] = reprs[i];
}

// One block = one term, 8 waves (512 threads), all 4 layers fused.
// Wave (wr,wc): wr=row-half (32 rows), wc=col-quarter (64 cols). 2 waves/SIMD.
// Attention: wave handles q-stripe wc of head wr (heads concurrent across row-waves).
// Register budget: ~250/thread (128 VGPR + ~128 AGPR, gfx950 unified file) -> no spill.
// NOTE (structural ceiling): occupancy steps are power-of-2 in total regs (waves/SIMD
// halve at 64/128/256); demand >128 pins 2 waves/SIMD for any variant of this dataflow.
__global__ __launch_bounds__(512, 2)
void encode_k(const int* __restrict__ tokens, const void* __restrict__ pad,
              const void* __restrict__ refm, const int* __restrict__ boolflag,
              const float* __restrict__ storage, const u16* __restrict__ embB,
              const u16* __restrict__ WqF, const u16* __restrict__ WkF,
              const u16* __restrict__ WvF, const u16* __restrict__ WoF,
              const u16* __restrict__ W1F, const float* __restrict__ b1,
              const u16* __restrict__ W2F, const float* __restrict__ b2,
              const float* __restrict__ ln1s, const float* __restrict__ ln1b,
              const float* __restrict__ ln2s, const float* __restrict__ ln2b,
              const int* __restrict__ list, const int* __restrict__ cnt,
              float* __restrict__ outCLS)
{
  int term;
  if (list){
    if ((int)blockIdx.x >= *cnt) return;
    term = list[blockIdx.x];
  } else {
    term = blockIdx.x;
  }
  const int flag = *boolflag;

  __shared__ u16 sXb[64 * 256];        // 32 KB bf16 X (swizzled)
  __shared__ u16 sPoolA[64 * 136];     // sQK | FFN hidden buf 0 (17.4 KB)
  __shared__ u16 sPoolB[64 * 72 * 2];  // sVT | sO (18 KB)
  __shared__ u16 sPbuf[2 * 64 * 72];   // per-head P | FFN hidden buf 1 (18 KB)
  __shared__ float sStat[64][8];
  __shared__ float sMask[64];
  __shared__ int sTok[192];
  __shared__ int sRef[64];

  u16 (*sQK)[136] = (u16(*)[136])sPoolA;
  u16 (*sVT)[72]  = (u16(*)[72])sPoolB;
  u16 (*sO)[72]   = (u16(*)[72])(sPoolB + 64*72);
  u16 (*sH0)[136] = (u16(*)[136])sPoolA;
  u16 (*sH1)[136] = (u16(*)[136])sPbuf;

  const int tid = threadIdx.x;
  const int w = tid >> 6, lane = tid & 63, lg = lane >> 4, li = lane & 15;
  const int wr = w >> 2, wc = w & 3;
  const int rbase = 32 * wr;           // this wave's row base
  const f32x4 zero4 = {0.f, 0.f, 0.f, 0.f};

  if (tid < 192) sTok[tid] = tokens[term * 192 + tid];
  if (tid < 64){
    sMask[tid] = getb(pad, term * 64 + tid, flag) ? 0.f : -1e9f;
    sRef[tid] = getb(refm, term * 64 + tid, flag) ? 1 : 0;
  }
  SBAR();

  // build X: 512 threads -> two row-halves in parallel
  {
    int col = tid & 255, rh = tid >> 8;
    #pragma unroll 4
    for (int s = 32*rh; s < 32*rh + 32; ++s){
      float v;
      if (sRef[s]){
        v = storage[sTok[3*s + 1] * 256 + col];
      } else {
        v = bf2f(embB[sTok[3*s + 0] * 256 + col])
          + bf2f(embB[(2048 + sTok[3*s + 1]) * 256 + col])
          + bf2f(embB[(4096 + sTok[3*s + 2]) * 256 + col]);
      }
      sXb[xoff(s, col)] = (u16)f2bf(v);
    }
  }
  SBAR();

  // X residual in registers at this thread's C-fragment positions
  float xres[2][4][4];
  #pragma unroll
  for (int rt = 0; rt < 2; ++rt)
    #pragma unroll
    for (int ctl = 0; ctl < 4; ++ctl)
      #pragma unroll
      for (int r = 0; r < 4; ++r)
        xres[rt][ctl][r] = bf2f(sXb[xoff(rbase + 16*rt + 4*lg + r, 64*wc + 16*ctl + li)]);

  auto ldA = [&](int rt, int kk) -> bf16x8 {
    return *(const bf16x8*)&sXb[(rbase + 16*rt + li) * 256 + (((4*kk + lg) ^ (li & 7)) << 3)];
  };

  for (int l = 0; l < 4; ++l){
    // ================= attention (incremental Wo accumulate) =================
    f32x4 ga[2][4];
    #pragma unroll
    for (int rt = 0; rt < 2; ++rt)
      #pragma unroll
      for (int c = 0; c < 4; ++c) ga[rt][c] = zero4;

    for (int hp = 0; hp < 4; ++hp){
      // ---- QKV GEMM (local cols 0..191 = Q|K|V; wave cols 48*wc..48*wc+47)
      f32x4 acc[2][3];
      #pragma unroll
      for (int rt = 0; rt < 2; ++rt)
        #pragma unroll
        for (int c = 0; c < 3; ++c) acc[rt][c] = zero4;

      const u16* bF[3];
      #pragma unroll
      for (int ctl = 0; ctl < 3; ++ctl){
        int c = 48 * wc + 16 * ctl;
        int mm = c >> 6;                       // 0:Q 1:K 2:V
        int nt = hp * 4 + ((c & 63) >> 4);
        const u16* Wt = (mm == 0) ? WqF : ((mm == 1) ? WkF : WvF);
        bF[ctl] = Wt + (((size_t)(l * 16 + nt) * 8) * 64 + lane) * 8;
      }
      bf16x8 bq[8][3];
      #pragma unroll
      for (int kt = 0; kt < 8; ++kt)
        #pragma unroll
        for (int ctl = 0; ctl < 3; ++ctl)
          bq[kt][ctl] = *(const bf16x8*)(bF[ctl] + (size_t)kt * 512);
      #pragma unroll
      for (int kt = 0; kt < 8; ++kt){
        bf16x8 a[2];
        #pragma unroll
        for (int rt = 0; rt < 2; ++rt) a[rt] = ldA(rt, kt);
        #pragma unroll
        for (int ctl = 0; ctl < 3; ++ctl)
          #pragma unroll
          for (int rt = 0; rt < 2; ++rt)
            acc[rt][ctl] = __builtin_amdgcn_mfma_f32_16x16x32_bf16(a[rt], bq[kt][ctl], acc[rt][ctl], 0, 0, 0);
      }
      // ---- scatter Q|K to sQK, V^T to sVT
      #pragma unroll
      for (int rt = 0; rt < 2; ++rt)
        #pragma unroll
        for (int ctl = 0; ctl < 3; ++ctl){
          int c = 48*wc + 16*ctl;
          if (c < 128){
            #pragma unroll
            for (int r = 0; r < 4; ++r)
              sQK[rbase + 16*rt + 4*lg + r][c + li] = (u16)f2bf(acc[rt][ctl][r]);
          } else {
            s16x4 pk;
            #pragma unroll
            for (int r = 0; r < 4; ++r) pk[r] = f2bf(acc[rt][ctl][r]);
            *(s16x4*)&sVT[c + li - 128][rbase + 16*rt + 4*lg] = pk;
          }
        }
      // prefetch Wo B-fragments before the barrier (consumed after attention)
      bf16x8 woB[2][4];
      #pragma unroll
      for (int kt2 = 0; kt2 < 2; ++kt2)
        #pragma unroll
        for (int ctl = 0; ctl < 4; ++ctl)
          woB[kt2][ctl] = *(const bf16x8*)(WoF +
              (((size_t)(l*16 + 4*wc + ctl) * 8 + 2*hp + kt2) * 64 + lane) * 8);
      SBAR();   // post-scatter: sQK/sVT visible

      // ---- attention: this wave = q-stripe wc of head wr
      {
        const int hh = wr, qs = wc;
        u16 (*sP)[72] = (u16(*)[72])(sPbuf + hh * 64 * 72);
        bf16x8 aq = *(const bf16x8*)&sQK[16*qs + li][32*hh + 8*lg];
        f32x4 sc[4];
        #pragma unroll
        for (int ct = 0; ct < 4; ++ct){
          bf16x8 bk = *(const bf16x8*)&sQK[16*ct + li][64 + 32*hh + 8*lg];
          sc[ct] = __builtin_amdgcn_mfma_f32_16x16x32_bf16(aq, bk, zero4, 0, 0, 0);
        }
        float sv[4][4];
        #pragma unroll
        for (int ct = 0; ct < 4; ++ct){
          float mk = sMask[16*ct + li];
          #pragma unroll
          for (int r = 0; r < 4; ++r) sv[ct][r] = sc[ct][r] * 0.17677669529663687f + mk;
        }
        #pragma unroll
        for (int r = 0; r < 4; ++r){
          float m = fmaxf(fmaxf(sv[0][r], sv[1][r]), fmaxf(sv[2][r], sv[3][r]));
          #pragma unroll
          for (int o = 1; o < 16; o <<= 1) m = fmaxf(m, __shfl_xor(m, o, 64));
          float s0 = 0.f;
          #pragma unroll
          for (int ct = 0; ct < 4; ++ct){ float e = __expf(sv[ct][r] - m); sv[ct][r] = e; s0 += e; }
          #pragma unroll
          for (int o = 1; o < 16; o <<= 1) s0 += __shfl_xor(s0, o, 64);
          float inv = 1.f / s0;
          #pragma unroll
          for (int ct = 0; ct < 4; ++ct) sv[ct][r] *= inv;
        }
        // P wave-private (head hh, stripe qs): no barriers needed
        #pragma unroll
        for (int ct = 0; ct < 4; ++ct)
          #pragma unroll
          for (int r = 0; r < 4; ++r)
            sP[16*qs + 4*lg + r][16*ct + li] = (u16)f2bf(sv[ct][r]);
        f32x4 oa[2] = {zero4, zero4};
        #pragma unroll
        for (int kt = 0; kt < 2; ++kt){
          bf16x8 ap = *(const bf16x8*)&sP[16*qs + li][32*kt + 8*lg];
          #pragma unroll
          for (int ct = 0; ct < 2; ++ct){
            bf16x8 bv = *(const bf16x8*)&sVT[32*hh + 16*ct + li][32*kt + 8*lg];
            oa[ct] = __builtin_amdgcn_mfma_f32_16x16x32_bf16(ap, bv, oa[ct], 0, 0, 0);
          }
        }
        #pragma unroll
        for (int ct = 0; ct < 2; ++ct)
          #pragma unroll
          for (int r = 0; r < 4; ++r)
            sO[16*qs + 4*lg + r][32*hh + 16*ct + li] = (u16)f2bf(oa[ct][r]);
      }
      SBAR();   // sO complete (also guards next hp's scatter)
      // partial Wo: ga += O[:, 64hp:64hp+64) @ Wo[64hp:64hp+64, :]
      #pragma unroll
      for (int kt2 = 0; kt2 < 2; ++kt2){
        bf16x8 a[2];
        #pragma unroll
        for (int rt = 0; rt < 2; ++rt)
          a[rt] = *(const bf16x8*)&sO[rbase + 16*rt + li][32*kt2 + 8*lg];
        #pragma unroll
        for (int ctl = 0; ctl < 4; ++ctl)
          #pragma unroll
          for (int rt = 0; rt < 2; ++rt)
            ga[rt][ctl] = __builtin_amdgcn_mfma_f32_16x16x32_bf16(a[rt], woB[kt2][ctl], ga[rt][ctl], 0, 0, 0);
      }
    } // hp

    // ================= residual + LN1 (regs -> sXb) =================
    {
      float g4[4], bb4[4];
      #pragma unroll
      for (int ctl = 0; ctl < 4; ++ctl){
        int col = 64*wc + 16*ctl + li;
        g4[ctl] = ln1s[l*256 + col]; bb4[ctl] = ln1b[l*256 + col];
      }
      float s1v[2][4], s2v[2][4];
      #pragma unroll
      for (int rt = 0; rt < 2; ++rt)
        #pragma unroll
        for (int r = 0; r < 4; ++r){
          float t1 = 0.f, t2 = 0.f;
          #pragma unroll
          for (int ctl = 0; ctl < 4; ++ctl){
            float y = ga[rt][ctl][r] + xres[rt][ctl][r];
            ga[rt][ctl][r] = y; t1 += y; t2 += y * y;
          }
          #pragma unroll
          for (int o = 1; o < 16; o <<= 1){ t1 += __shfl_xor(t1, o, 64); t2 += __shfl_xor(t2, o, 64); }
          s1v[rt][r] = t1; s2v[rt][r] = t2;
        }
      if (li == 0){
        #pragma unroll
        for (int rt = 0; rt < 2; ++rt)
          #pragma unroll
          for (int r = 0; r < 4; ++r){
            sStat[rbase + 16*rt + 4*lg + r][wc] = s1v[rt][r];
            sStat[rbase + 16*rt + 4*lg + r][4 + wc] = s2v[rt][r];
          }
      }
      SBAR();
      #pragma unroll
      for (int rt = 0; rt < 2; ++rt)
        #pragma unroll
        for (int r = 0; r < 4; ++r){
          int row = rbase + 16*rt + 4*lg + r;
          float su = sStat[row][0] + sStat[row][1] + sStat[row][2] + sStat[row][3];
          float sq = sStat[row][4] + sStat[row][5] + sStat[row][6] + sStat[row][7];
          float mean = su * (1.f / 256.f);
          float var = sq * (1.f / 256.f) - mean * mean;
          float rs = rsqrtf(var + 1e-5f);
          #pragma unroll
          for (int ctl = 0; ctl < 4; ++ctl){
            int col = 64*wc + 16*ctl + li;
            float nv = (ga[rt][ctl][r] - mean) * rs * g4[ctl] + bb4[ctl];
            xres[rt][ctl][r] = nv;
            sXb[xoff(row, col)] = (u16)f2bf(nv);
          }
        }
      SBAR();
    }

    // ================= FFN: double-buffered hidden, pipelined W loads =================
    {
      float b1v[8][2];
      #pragma unroll
      for (int ch = 0; ch < 8; ++ch)
        #pragma unroll
        for (int ctl = 0; ctl < 2; ++ctl)
          b1v[ch][ctl] = b1[l*1024 + 128*ch + 32*wc + 16*ctl + li];

      bf16x8 w1f[2][8];
      auto loadW1 = [&](int ch){
        #pragma unroll
        for (int ctl = 0; ctl < 2; ++ctl){
          const u16* p0 = W1F + (((size_t)(l*64 + 8*ch + 2*wc + ctl) * 8) * 64 + lane) * 8;
          #pragma unroll
          for (int kt = 0; kt < 8; ++kt)
            w1f[ctl][kt] = *(const bf16x8*)(p0 + (size_t)kt * 512);
        }
      };
      auto mfma1 = [&](f32x4 (*h)[2]){
        #pragma unroll
        for (int rt = 0; rt < 2; ++rt){ h[rt][0] = zero4; h[rt][1] = zero4; }
        #pragma unroll
        for (int kt = 0; kt < 8; ++kt){
          bf16x8 a[2];
          #pragma unroll
          for (int rt = 0; rt < 2; ++rt) a[rt] = ldA(rt, kt);
          #pragma unroll
          for (int ctl = 0; ctl < 2; ++ctl)
            #pragma unroll
            for (int rt = 0; rt < 2; ++rt)
              h[rt][ctl] = __builtin_amdgcn_mfma_f32_16x16x32_bf16(a[rt], w1f[ctl][kt], h[rt][ctl], 0, 0, 0);
        }
      };

      f32x4 fa[2][4];
      #pragma unroll
      for (int rt = 0; rt < 2; ++rt)
        #pragma unroll
        for (int c = 0; c < 4; ++c) fa[rt][c] = zero4;

      f32x4 haA[2][2], haB[2][2];
      loadW1(0);
      mfma1(haA);

      #pragma unroll
      for (int ch = 0; ch < 8; ++ch){
        f32x4 (*cur)[2] = (ch & 1) ? haB : haA;
        f32x4 (*nxt)[2] = (ch & 1) ? haA : haB;
        u16 (*sHc)[136] = (ch & 1) ? sH1 : sH0;
        #pragma unroll
        for (int rt = 0; rt < 2; ++rt)
          #pragma unroll
          for (int ctl = 0; ctl < 2; ++ctl)
            #pragma unroll
            for (int r = 0; r < 4; ++r){
              float v = cur[rt][ctl][r] + b1v[ch][ctl];
              sHc[rbase + 16*rt + 4*lg + r][32*wc + 16*ctl + li] = (u16)f2bf(fmaxf(v, 0.f));
            }
        // pre-barrier issue of W2(ch) first half; survives the raw barrier
        bf16x8 w2a[2][4];
        #pragma unroll
        for (int kt = 0; kt < 2; ++kt)
          #pragma unroll
          for (int ctl = 0; ctl < 4; ++ctl)
            w2a[kt][ctl] = *(const bf16x8*)(W2F +
                (((size_t)(l*16 + 4*wc + ctl) * 32 + 4*ch + kt) * 64 + lane) * 8);
        SBAR();    // hidden chunk visible
        if (ch < 7) loadW1(ch + 1);
        // GEMM2(ch) first half
        #pragma unroll
        for (int kt = 0; kt < 2; ++kt){
          bf16x8 a[2];
          #pragma unroll
          for (int rt = 0; rt < 2; ++rt)
            a[rt] = *(const bf16x8*)&sHc[rbase + 16*rt + li][32*kt + 8*lg];
          #pragma unroll
          for (int ctl = 0; ctl < 4; ++ctl)
            #pragma unroll
            for (int rt = 0; rt < 2; ++rt)
              fa[rt][ctl] = __builtin_amdgcn_mfma_f32_16x16x32_bf16(a[rt], w2a[kt][ctl], fa[rt][ctl], 0, 0, 0);
        }
        // GEMM2(ch) second half
        #pragma unroll
        for (int kt = 2; kt < 4; ++kt){
          bf16x8 br[4];
          #pragma unroll
          for (int ctl = 0; ctl < 4; ++ctl)
            br[ctl] = *(const bf16x8*)(W2F +
                (((size_t)(l*16 + 4*wc + ctl) * 32 + 4*ch + kt) * 64 + lane) * 8);
          bf16x8 a[2];
          #pragma unroll
          for (int rt = 0; rt < 2; ++rt)
            a[rt] = *(const bf16x8*)&sHc[rbase + 16*rt + li][32*kt + 8*lg];
          #pragma unroll
          for (int ctl = 0; ctl < 4; ++ctl)
            #pragma unroll
            for (int rt = 0; rt < 2; ++rt)
              fa[rt][ctl] = __builtin_amdgcn_mfma_f32_16x16x32_bf16(a[rt], br[ctl], fa[rt][ctl], 0, 0, 0);
        }
        if (ch < 7) mfma1(nxt);
      }

      // ---- residual + bias + LN2
      float g4[4], bb4[4], b2v[4];
      #pragma unroll
      for (int ctl = 0; ctl < 4; ++ctl){
        int col = 64*wc + 16*ctl + li;
        g4[ctl] = ln2s[l*256 + col]; bb4[ctl] = ln2b[l*256 + col]; b2v[ctl] = b2[l*256 + col];
      }
      float s1v[2][4], s2v[2][4];
      #pragma unroll
      for (int rt = 0; rt < 2; ++rt)
        #pragma unroll
        for (int r = 0; r < 4; ++r){
          float t1 = 0.f, t2 = 0.f;
          #pragma unroll
          for (int ctl = 0; ctl < 4; ++ctl){
            float y = fa[rt][ctl][r] + xres[rt][ctl][r] + b2v[ctl];
            fa[rt][ctl][r] = y; t1 += y; t2 += y * y;
          }
          #pragma unroll
          for (int o = 1; o < 16; o <<= 1){ t1 += __shfl_xor(t1, o, 64); t2 += __shfl_xor(t2, o, 64); }
          s1v[rt][r] = t1; s2v[rt][r] = t2;
        }
      if (li == 0){
        #pragma unroll
        for (int rt = 0; rt < 2; ++rt)
          #pragma unroll
          for (int r = 0; r < 4; ++r){
            sStat[rbase + 16*rt + 4*lg + r][wc] = s1v[rt][r];
            sStat[rbase + 16*rt + 4*lg + r][4 + wc] = s2v[rt][r];
          }
      }
      SBAR();
      #pragma unroll
      for (int rt = 0; rt < 2; ++rt)
        #pragma unroll
        for (int r = 0; r < 4; ++r){
          int row = rbase + 16*rt + 4*lg + r;
          float su = sStat[row][0] + sStat[row][1] + sStat[row][2] + sStat[row][3];
          float sq = sStat[row][4] + sStat[row][5] + sStat[row][6] + sStat[row][7];
          float mean = su * (1.f / 256.f);
          float var = sq * (1.f / 256.f) - mean * mean;
          float rs = rsqrtf(var + 1e-5f);
          #pragma unroll
          for (int ctl = 0; ctl < 4; ++ctl){
            int col = 64*wc + 16*ctl + li;
            float nv = (fa[rt][ctl][r] - mean) * rs * g4[ctl] + bb4[ctl];
            xres[rt][ctl][r] = nv;
            sXb[xoff(row, col)] = (u16)f2bf(nv);
            if (l == 3 && outCLS && row == 0) outCLS[term * 256 + col] = nv;
          }
        }
      SBAR();
    }
  }
}

extern "C" void kernel_launch(void* const* d_in, const int* in_sizes, int n_in,
                              void* d_out, int out_size, void* d_ws, size_t ws_size,
                              hipStream_t stream)
{
  (void)in_sizes; (void)n_in; (void)out_size; (void)ws_size;
  const int* tokens_scope = (const int*)d_in[0];
  const int* tokens_hole  = (const int*)d_in[1];
  const void* pad_scope = d_in[2];
  const void* pad_hole  = d_in[3];
  const void* ref_scope = d_in[4];
  const void* ref_hole  = d_in[5];
  const int* scope_sort = (const int*)d_in[6];
  const int* scope_pos  = (const int*)d_in[7];
  const float* emb  = (const float*)d_in[8];
  const float* Wq   = (const float*)d_in[9];
  const float* Wk   = (const float*)d_in[10];
  const float* Wv   = (const float*)d_in[11];
  const float* Wo   = (const float*)d_in[12];
  const float* ln1s = (const float*)d_in[13];
  const float* ln1b = (const float*)d_in[14];
  const float* W1   = (const float*)d_in[15];
  const float* b1   = (const float*)d_in[16];
  const float* W2   = (const float*)d_in[17];
  const float* b2   = (const float*)d_in[18];
  const float* ln2s = (const float*)d_in[19];
  const float* ln2b = (const float*)d_in[20];

  char* p = (char*)d_ws;
  float* reprs  = (float*)p; p += (size_t)2048*256*4;
  float* encCLS = (float*)p; p += (size_t)2048*256*4;
  u16* WqF = (u16*)p; p += (size_t)4*256*256*2;
  u16* WkF = (u16*)p; p += (size_t)4*256*256*2;
  u16* WvF = (u16*)p; p += (size_t)4*256*256*2;
  u16* WoF = (u16*)p; p += (size_t)4*256*256*2;
  u16* W1F = (u16*)p; p += (size_t)4*256*1024*2;
  u16* W2F = (u16*)p; p += (size_t)4*256*1024*2;
  u16* embB = (u16*)p; p += (size_t)3*2048*256*2;
  int* lists = (int*)p; p += (size_t)4*2048*4;
  int* counts = (int*)p; p += 64;
  int* flag = (int*)p; p += 16;

  hipLaunchKernelGGL(detect_bool_k, dim3(1), dim3(64), 0, stream, pad_scope, flag, counts);
  hipLaunchKernelGGL(prep_k, dim3(20480), dim3(256), 0, stream,
                     emb, embB, Wq, Wk, Wv, Wo, W1, W2,
                     WqF, WkF, WvF, WoF, W1F, W2F, scope_pos, reprs);
  hipLaunchKernelGGL(compact_k, dim3(8), dim3(256), 0, stream, scope_sort, lists, counts);

  for (int r = 0; r < 4; ++r){
    hipLaunchKernelGGL(encode_k, dim3(2048), dim3(512), 0, stream,
      tokens_scope, pad_scope, ref_scope, flag, reprs, embB,
      WqF, WkF, WvF, WoF, W1F, b1, W2F, b2, ln1s, ln1b, ln2s, ln2b,
      lists + (size_t)r*2048, counts + r, encCLS);
    hipLaunchKernelGGL(update_k, dim3(2048), dim3(256), 0, stream, scope_sort, encCLS, reprs, r);
  }
  hipLaunchKernelGGL(encode_k, dim3(512), dim3(512), 0, stream,
      tokens_hole, pad_hole, ref_hole, flag, reprs, embB,
      WqF, WkF, WvF, WoF, W1F, b1, W2F, b2, ln1s, ln1b, ln2s, ln2b,
      (const int*)nullptr, (const int*)nullptr, (float*)d_out + (size_t)2048*256);
  hipLaunchKernelGGL(writeout_k, dim3(2048), dim3(256), 0, stream, reprs, (float*)d_out);
}

// Round 15
// 2703.207 us; speedup vs baseline: 1.9196x; 1.0265x over previous
//
#include <hip/hip_runtime.h>
#include <stdint.h>
#include <math.h>

typedef __attribute__((ext_vector_type(8))) short bf16x8;
typedef __attribute__((ext_vector_type(4))) short s16x4;
typedef __attribute__((ext_vector_type(4))) float f32x4;
typedef unsigned short u16;

// raw barrier: LDS drain only; global (vmcnt) prefetches stay in flight
#define SBAR() asm volatile("s_waitcnt lgkmcnt(0)\ns_barrier" ::: "memory")

__device__ __forceinline__ short f2bf(float f){
  union { float f; uint32_t u; } v; v.f = f;
  uint32_t r = v.u + 0x7FFFu + ((v.u >> 16) & 1u);
  return (short)(r >> 16);
}
__device__ __forceinline__ float bf2f(u16 b){
  union { uint32_t u; float f; } v; v.u = ((uint32_t)b) << 16; return v.f;
}
__device__ __forceinline__ bool getb(const void* p, int i, int flag){
  if (flag) return ((const unsigned char*)p)[i] != 0;
  return ((const int*)p)[i] != 0;
}
// XOR-swizzled offset into the bf16 X buffer [64 rows][256 cols]
__device__ __forceinline__ int xoff(int row, int col){
  int g = (col >> 3) ^ (row & 7);
  return row * 256 + (g << 3) + (col & 7);
}

__global__ void detect_bool_k(const void* pad, int* flag, int* counts){
  if (threadIdx.x < 4) counts[threadIdx.x] = 0;
  if (threadIdx.x == 0){
    const unsigned char* b = (const unsigned char*)pad;
    int f = 0;
    for (int i = 1; i < 64; ++i) if (i & 3) f |= (b[i] != 0) ? 1 : 0;
    *flag = f;
  }
}

// ONE prologue kernel:
//   blocks [0,6144): emb f32 -> bf16 straight convert
//   blocks [6144,18432): pack six W tensors into MFMA-fragment-linear bf16
//     dst[(((m*(N/16)+nt)*(K/32)+kt)*64 + lane)*8 + j] = W[m][32kt+8lg+j][16nt+li]
//   blocks [18432,20480): sinusoidal pos-enc init of reprs
__global__ void prep_k(const float* __restrict__ emb, u16* __restrict__ embB,
                       const float* __restrict__ Wq, const float* __restrict__ Wk,
                       const float* __restrict__ Wv, const float* __restrict__ Wo,
                       const float* __restrict__ W1, const float* __restrict__ W2,
                       u16* __restrict__ WqF, u16* __restrict__ WkF,
                       u16* __restrict__ WvF, u16* __restrict__ WoF,
                       u16* __restrict__ W1F, u16* __restrict__ W2F,
                       const int* __restrict__ pos, float* __restrict__ reprs){
  int b = blockIdx.x;
  if (b < 6144){
    long i = (long)b * 256 + threadIdx.x;
    embB[i] = (u16)f2bf(emb[i]);
    return;
  }
  if (b >= 18432){
    int n = b - 18432, d = threadIdx.x;
    double p = (double)pos[n];
    int i = (d < 128) ? d : d - 128;
    double ang = p / pow(500.0, (2.0 * (double)i) / 256.0);
    reprs[n * 256 + d] = (d < 128) ? (float)sin(ang) : (float)cos(ang);
    return;
  }
  b -= 6144;
  const float* src; u16* dst; int K, N;
  if (b < 4096){
    int t = b >> 10; b &= 1023;
    if (t == 0){ src = Wq; dst = WqF; }
    else if (t == 1){ src = Wk; dst = WkF; }
    else if (t == 2){ src = Wv; dst = WvF; }
    else { src = Wo; dst = WoF; }
    K = 256; N = 256;
  } else if (b < 8192){ src = W1; dst = W1F; K = 256; N = 1024; b -= 4096; }
  else { src = W2; dst = W2F; K = 1024; N = 256; b -= 8192; }
  long idx = (long)b * 256 + threadIdx.x;
  int j = (int)(idx & 7);
  int lane = (int)((idx >> 3) & 63);
  long t2a = idx >> 9;
  int KT = K >> 5;
  int kt = (int)(t2a % KT);
  long t2 = t2a / KT;
  int NT = N >> 4;
  int nt = (int)(t2 % NT);
  int m = (int)(t2 / NT);
  int li = lane & 15, lg = lane >> 4;
  int k = 32*kt + 8*lg + j, n = 16*nt + li;
  dst[idx] = (u16)f2bf(src[((long)m * K + k) * N + n]);
}

__global__ void compact_k(const int* __restrict__ sortv, int* __restrict__ lists,
                          int* __restrict__ counts){
  int t = blockIdx.x * 256 + threadIdx.x;
  int r = sortv[t];
  int pos = atomicAdd(&counts[r], 1);
  lists[r * 2048 + pos] = t;
}

// live-list driven: only cnt blocks do work
__global__ void update_k(const int* __restrict__ list, const int* __restrict__ cnt,
                         const float* __restrict__ encCLS, float* __restrict__ reprs){
  if ((int)blockIdx.x >= *cnt) return;
  int t = list[blockIdx.x];
  reprs[t * 256 + threadIdx.x] += encCLS[t * 256 + threadIdx.x];
}

__global__ void writeout_k(const float* __restrict__ reprs, float* __restrict__ out){
  int i = blockIdx.x * 256 + threadIdx.x;
  out[i] = reprs[i];
}

// One block = one term, 8 waves (512 threads), all 4 layers fused.
// Wave (wr,wc): wr=row-half (32 rows), wc=col-quarter (64 cols). 2 waves/SIMD.
// Attention: wave handles q-stripe wc of head wr (heads concurrent across row-waves).
// Register budget: ~250/thread (128 VGPR + ~128 AGPR, gfx950 unified file) -> no spill.
// Structural ceiling: occupancy steps are power-of-2 in total regs; demand >128 pins
// 2 waves/SIMD for any variant of this dataflow (R6/R8/R9/R10/R13 all spilled).
// Softmax: no max-subtraction (post-LN scores ~N(0,1), |s|<<85 -> exp safe in f32);
// halves the serial cross-lane reduce chain.
__global__ __launch_bounds__(512, 2)
void encode_k(const int* __restrict__ tokens, const void* __restrict__ pad,
              const void* __restrict__ refm, const int* __restrict__ boolflag,
              const float* __restrict__ storage, const u16* __restrict__ embB,
              const u16* __restrict__ WqF, const u16* __restrict__ WkF,
              const u16* __restrict__ WvF, const u16* __restrict__ WoF,
              const u16* __restrict__ W1F, const float* __restrict__ b1,
              const u16* __restrict__ W2F, const float* __restrict__ b2,
              const float* __restrict__ ln1s, const float* __restrict__ ln1b,
              const float* __restrict__ ln2s, const float* __restrict__ ln2b,
              const int* __restrict__ list, const int* __restrict__ cnt,
              float* __restrict__ outCLS)
{
  int term;
  if (list){
    if ((int)blockIdx.x >= *cnt) return;
    term = list[blockIdx.x];
  } else {
    term = blockIdx.x;
  }
  const int flag = *boolflag;

  __shared__ u16 sXb[64 * 256];        // 32 KB bf16 X (swizzled)
  __shared__ u16 sPoolA[64 * 136];     // sQK | FFN hidden buf 0 (17.4 KB)
  __shared__ u16 sPoolB[64 * 72 * 2];  // sVT | sO (18 KB)
  __shared__ u16 sPbuf[2 * 64 * 72];   // per-head P | FFN hidden buf 1 (18 KB)
  __shared__ float sStat[64][8];
  __shared__ float sMask[64];
  __shared__ int sTok[192];
  __shared__ int sRef[64];

  u16 (*sQK)[136] = (u16(*)[136])sPoolA;
  u16 (*sVT)[72]  = (u16(*)[72])sPoolB;
  u16 (*sO)[72]   = (u16(*)[72])(sPoolB + 64*72);
  u16 (*sH0)[136] = (u16(*)[136])sPoolA;
  u16 (*sH1)[136] = (u16(*)[136])sPbuf;

  const int tid = threadIdx.x;
  const int w = tid >> 6, lane = tid & 63, lg = lane >> 4, li = lane & 15;
  const int wr = w >> 2, wc = w & 3;
  const int rbase = 32 * wr;           // this wave's row base
  const f32x4 zero4 = {0.f, 0.f, 0.f, 0.f};

  if (tid < 192) sTok[tid] = tokens[term * 192 + tid];
  if (tid < 64){
    sMask[tid] = getb(pad, term * 64 + tid, flag) ? 0.f : -1e9f;
    sRef[tid] = getb(refm, term * 64 + tid, flag) ? 1 : 0;
  }
  SBAR();

  // build X: 512 threads -> two row-halves in parallel
  {
    int col = tid & 255, rh = tid >> 8;
    #pragma unroll 4
    for (int s = 32*rh; s < 32*rh + 32; ++s){
      float v;
      if (sRef[s]){
        v = storage[sTok[3*s + 1] * 256 + col];
      } else {
        v = bf2f(embB[sTok[3*s + 0] * 256 + col])
          + bf2f(embB[(2048 + sTok[3*s + 1]) * 256 + col])
          + bf2f(embB[(4096 + sTok[3*s + 2]) * 256 + col]);
      }
      sXb[xoff(s, col)] = (u16)f2bf(v);
    }
  }
  SBAR();

  // X residual in registers at this thread's C-fragment positions
  float xres[2][4][4];
  #pragma unroll
  for (int rt = 0; rt < 2; ++rt)
    #pragma unroll
    for (int ctl = 0; ctl < 4; ++ctl)
      #pragma unroll
      for (int r = 0; r < 4; ++r)
        xres[rt][ctl][r] = bf2f(sXb[xoff(rbase + 16*rt + 4*lg + r, 64*wc + 16*ctl + li)]);

  auto ldA = [&](int rt, int kk) -> bf16x8 {
    return *(const bf16x8*)&sXb[(rbase + 16*rt + li) * 256 + (((4*kk + lg) ^ (li & 7)) << 3)];
  };

  for (int l = 0; l < 4; ++l){
    // ================= attention (incremental Wo accumulate) =================
    f32x4 ga[2][4];
    #pragma unroll
    for (int rt = 0; rt < 2; ++rt)
      #pragma unroll
      for (int c = 0; c < 4; ++c) ga[rt][c] = zero4;

    for (int hp = 0; hp < 4; ++hp){
      // ---- QKV GEMM (local cols 0..191 = Q|K|V; wave cols 48*wc..48*wc+47)
      f32x4 acc[2][3];
      #pragma unroll
      for (int rt = 0; rt < 2; ++rt)
        #pragma unroll
        for (int c = 0; c < 3; ++c) acc[rt][c] = zero4;

      const u16* bF[3];
      #pragma unroll
      for (int ctl = 0; ctl < 3; ++ctl){
        int c = 48 * wc + 16 * ctl;
        int mm = c >> 6;                       // 0:Q 1:K 2:V
        int nt = hp * 4 + ((c & 63) >> 4);
        const u16* Wt = (mm == 0) ? WqF : ((mm == 1) ? WkF : WvF);
        bF[ctl] = Wt + (((size_t)(l * 16 + nt) * 8) * 64 + lane) * 8;
      }
      bf16x8 bq[8][3];
      #pragma unroll
      for (int kt = 0; kt < 8; ++kt)
        #pragma unroll
        for (int ctl = 0; ctl < 3; ++ctl)
          bq[kt][ctl] = *(const bf16x8*)(bF[ctl] + (size_t)kt * 512);
      #pragma unroll
      for (int kt = 0; kt < 8; ++kt){
        bf16x8 a[2];
        #pragma unroll
        for (int rt = 0; rt < 2; ++rt) a[rt] = ldA(rt, kt);
        #pragma unroll
        for (int ctl = 0; ctl < 3; ++ctl)
          #pragma unroll
          for (int rt = 0; rt < 2; ++rt)
            acc[rt][ctl] = __builtin_amdgcn_mfma_f32_16x16x32_bf16(a[rt], bq[kt][ctl], acc[rt][ctl], 0, 0, 0);
      }
      // ---- scatter Q|K to sQK, V^T to sVT
      #pragma unroll
      for (int rt = 0; rt < 2; ++rt)
        #pragma unroll
        for (int ctl = 0; ctl < 3; ++ctl){
          int c = 48*wc + 16*ctl;
          if (c < 128){
            #pragma unroll
            for (int r = 0; r < 4; ++r)
              sQK[rbase + 16*rt + 4*lg + r][c + li] = (u16)f2bf(acc[rt][ctl][r]);
          } else {
            s16x4 pk;
            #pragma unroll
            for (int r = 0; r < 4; ++r) pk[r] = f2bf(acc[rt][ctl][r]);
            *(s16x4*)&sVT[c + li - 128][rbase + 16*rt + 4*lg] = pk;
          }
        }
      // prefetch Wo B-fragments before the barrier (consumed after attention)
      bf16x8 woB[2][4];
      #pragma unroll
      for (int kt2 = 0; kt2 < 2; ++kt2)
        #pragma unroll
        for (int ctl = 0; ctl < 4; ++ctl)
          woB[kt2][ctl] = *(const bf16x8*)(WoF +
              (((size_t)(l*16 + 4*wc + ctl) * 8 + 2*hp + kt2) * 64 + lane) * 8);
      SBAR();   // post-scatter: sQK/sVT visible

      // ---- attention: this wave = q-stripe wc of head wr
      {
        const int hh = wr, qs = wc;
        u16 (*sP)[72] = (u16(*)[72])(sPbuf + hh * 64 * 72);
        bf16x8 aq = *(const bf16x8*)&sQK[16*qs + li][32*hh + 8*lg];
        f32x4 sc[4];
        #pragma unroll
        for (int ct = 0; ct < 4; ++ct){
          bf16x8 bk = *(const bf16x8*)&sQK[16*ct + li][64 + 32*hh + 8*lg];
          sc[ct] = __builtin_amdgcn_mfma_f32_16x16x32_bf16(aq, bk, zero4, 0, 0, 0);
        }
        // softmax WITHOUT max-subtraction: scores are post-LN, O(1); exp safe in f32.
        float sv[4][4];
        #pragma unroll
        for (int ct = 0; ct < 4; ++ct){
          float mk = sMask[16*ct + li];
          #pragma unroll
          for (int r = 0; r < 4; ++r)
            sv[ct][r] = __expf(sc[ct][r] * 0.17677669529663687f + mk);
        }
        #pragma unroll
        for (int r = 0; r < 4; ++r){
          float s0 = sv[0][r] + sv[1][r] + sv[2][r] + sv[3][r];
          #pragma unroll
          for (int o = 1; o < 16; o <<= 1) s0 += __shfl_xor(s0, o, 64);
          float inv = 1.f / s0;
          #pragma unroll
          for (int ct = 0; ct < 4; ++ct) sv[ct][r] *= inv;
        }
        // P wave-private (head hh, stripe qs): no barriers needed
        #pragma unroll
        for (int ct = 0; ct < 4; ++ct)
          #pragma unroll
          for (int r = 0; r < 4; ++r)
            sP[16*qs + 4*lg + r][16*ct + li] = (u16)f2bf(sv[ct][r]);
        f32x4 oa[2] = {zero4, zero4};
        #pragma unroll
        for (int kt = 0; kt < 2; ++kt){
          bf16x8 ap = *(const bf16x8*)&sP[16*qs + li][32*kt + 8*lg];
          #pragma unroll
          for (int ct = 0; ct < 2; ++ct){
            bf16x8 bv = *(const bf16x8*)&sVT[32*hh + 16*ct + li][32*kt + 8*lg];
            oa[ct] = __builtin_amdgcn_mfma_f32_16x16x32_bf16(ap, bv, oa[ct], 0, 0, 0);
          }
        }
        #pragma unroll
        for (int ct = 0; ct < 2; ++ct)
          #pragma unroll
          for (int r = 0; r < 4; ++r)
            sO[16*qs + 4*lg + r][32*hh + 16*ct + li] = (u16)f2bf(oa[ct][r]);
      }
      SBAR();   // sO complete (also guards next hp's scatter)
      // partial Wo: ga += O[:, 64hp:64hp+64) @ Wo[64hp:64hp+64, :]
      #pragma unroll
      for (int kt2 = 0; kt2 < 2; ++kt2){
        bf16x8 a[2];
        #pragma unroll
        for (int rt = 0; rt < 2; ++rt)
          a[rt] = *(const bf16x8*)&sO[rbase + 16*rt + li][32*kt2 + 8*lg];
        #pragma unroll
        for (int ctl = 0; ctl < 4; ++ctl)
          #pragma unroll
          for (int rt = 0; rt < 2; ++rt)
            ga[rt][ctl] = __builtin_amdgcn_mfma_f32_16x16x32_bf16(a[rt], woB[kt2][ctl], ga[rt][ctl], 0, 0, 0);
      }
    } // hp

    // ================= residual + LN1 (regs -> sXb) =================
    {
      float g4[4], bb4[4];
      #pragma unroll
      for (int ctl = 0; ctl < 4; ++ctl){
        int col = 64*wc + 16*ctl + li;
        g4[ctl] = ln1s[l*256 + col]; bb4[ctl] = ln1b[l*256 + col];
      }
      float s1v[2][4], s2v[2][4];
      #pragma unroll
      for (int rt = 0; rt < 2; ++rt)
        #pragma unroll
        for (int r = 0; r < 4; ++r){
          float t1 = 0.f, t2 = 0.f;
          #pragma unroll
          for (int ctl = 0; ctl < 4; ++ctl){
            float y = ga[rt][ctl][r] + xres[rt][ctl][r];
            ga[rt][ctl][r] = y; t1 += y; t2 += y * y;
          }
          #pragma unroll
          for (int o = 1; o < 16; o <<= 1){ t1 += __shfl_xor(t1, o, 64); t2 += __shfl_xor(t2, o, 64); }
          s1v[rt][r] = t1; s2v[rt][r] = t2;
        }
      if (li == 0){
        #pragma unroll
        for (int rt = 0; rt < 2; ++rt)
          #pragma unroll
          for (int r = 0; r < 4; ++r){
            sStat[rbase + 16*rt + 4*lg + r][wc] = s1v[rt][r];
            sStat[rbase + 16*rt + 4*lg + r][4 + wc] = s2v[rt][r];
          }
      }
      SBAR();
      #pragma unroll
      for (int rt = 0; rt < 2; ++rt)
        #pragma unroll
        for (int r = 0; r < 4; ++r){
          int row = rbase + 16*rt + 4*lg + r;
          float su = sStat[row][0] + sStat[row][1] + sStat[row][2] + sStat[row][3];
          float sq = sStat[row][4] + sStat[row][5] + sStat[row][6] + sStat[row][7];
          float mean = su * (1.f / 256.f);
          float var = sq * (1.f / 256.f) - mean * mean;
          float rs = rsqrtf(var + 1e-5f);
          #pragma unroll
          for (int ctl = 0; ctl < 4; ++ctl){
            int col = 64*wc + 16*ctl + li;
            float nv = (ga[rt][ctl][r] - mean) * rs * g4[ctl] + bb4[ctl];
            xres[rt][ctl][r] = nv;
            sXb[xoff(row, col)] = (u16)f2bf(nv);
          }
        }
      SBAR();
    }

    // ================= FFN: double-buffered hidden, pipelined W loads =================
    {
      float b1v[8][2];
      #pragma unroll
      for (int ch = 0; ch < 8; ++ch)
        #pragma unroll
        for (int ctl = 0; ctl < 2; ++ctl)
          b1v[ch][ctl] = b1[l*1024 + 128*ch + 32*wc + 16*ctl + li];

      bf16x8 w1f[2][8];
      auto loadW1 = [&](int ch){
        #pragma unroll
        for (int ctl = 0; ctl < 2; ++ctl){
          const u16* p0 = W1F + (((size_t)(l*64 + 8*ch + 2*wc + ctl) * 8) * 64 + lane) * 8;
          #pragma unroll
          for (int kt = 0; kt < 8; ++kt)
            w1f[ctl][kt] = *(const bf16x8*)(p0 + (size_t)kt * 512);
        }
      };
      auto mfma1 = [&](f32x4 (*h)[2]){
        #pragma unroll
        for (int rt = 0; rt < 2; ++rt){ h[rt][0] = zero4; h[rt][1] = zero4; }
        #pragma unroll
        for (int kt = 0; kt < 8; ++kt){
          bf16x8 a[2];
          #pragma unroll
          for (int rt = 0; rt < 2; ++rt) a[rt] = ldA(rt, kt);
          #pragma unroll
          for (int ctl = 0; ctl < 2; ++ctl)
            #pragma unroll
            for (int rt = 0; rt < 2; ++rt)
              h[rt][ctl] = __builtin_amdgcn_mfma_f32_16x16x32_bf16(a[rt], w1f[ctl][kt], h[rt][ctl], 0, 0, 0);
        }
      };

      f32x4 fa[2][4];
      #pragma unroll
      for (int rt = 0; rt < 2; ++rt)
        #pragma unroll
        for (int c = 0; c < 4; ++c) fa[rt][c] = zero4;

      f32x4 haA[2][2], haB[2][2];
      loadW1(0);
      mfma1(haA);

      #pragma unroll
      for (int ch = 0; ch < 8; ++ch){
        f32x4 (*cur)[2] = (ch & 1) ? haB : haA;
        f32x4 (*nxt)[2] = (ch & 1) ? haA : haB;
        u16 (*sHc)[136] = (ch & 1) ? sH1 : sH0;
        #pragma unroll
        for (int rt = 0; rt < 2; ++rt)
          #pragma unroll
          for (int ctl = 0; ctl < 2; ++ctl)
            #pragma unroll
            for (int r = 0; r < 4; ++r){
              float v = cur[rt][ctl][r] + b1v[ch][ctl];
              sHc[rbase + 16*rt + 4*lg + r][32*wc + 16*ctl + li] = (u16)f2bf(fmaxf(v, 0.f));
            }
        // pre-barrier issue of W2(ch) first half; survives the raw barrier
        bf16x8 w2a[2][4];
        #pragma unroll
        for (int kt = 0; kt < 2; ++kt)
          #pragma unroll
          for (int ctl = 0; ctl < 4; ++ctl)
            w2a[kt][ctl] = *(const bf16x8*)(W2F +
                (((size_t)(l*16 + 4*wc + ctl) * 32 + 4*ch + kt) * 64 + lane) * 8);
        SBAR();    // hidden chunk visible
        if (ch < 7) loadW1(ch + 1);
        // GEMM2(ch) first half
        #pragma unroll
        for (int kt = 0; kt < 2; ++kt){
          bf16x8 a[2];
          #pragma unroll
          for (int rt = 0; rt < 2; ++rt)
            a[rt] = *(const bf16x8*)&sHc[rbase + 16*rt + li][32*kt + 8*lg];
          #pragma unroll
          for (int ctl = 0; ctl < 4; ++ctl)
            #pragma unroll
            for (int rt = 0; rt < 2; ++rt)
              fa[rt][ctl] = __builtin_amdgcn_mfma_f32_16x16x32_bf16(a[rt], w2a[kt][ctl], fa[rt][ctl], 0, 0, 0);
        }
        // GEMM2(ch) second half
        #pragma unroll
        for (int kt = 2; kt < 4; ++kt){
          bf16x8 br[4];
          #pragma unroll
          for (int ctl = 0; ctl < 4; ++ctl)
            br[ctl] = *(const bf16x8*)(W2F +
                (((size_t)(l*16 + 4*wc + ctl) * 32 + 4*ch + kt) * 64 + lane) * 8);
          bf16x8 a[2];
          #pragma unroll
          for (int rt = 0; rt < 2; ++rt)
            a[rt] = *(const bf16x8*)&sHc[rbase + 16*rt + li][32*kt + 8*lg];
          #pragma unroll
          for (int ctl = 0; ctl < 4; ++ctl)
            #pragma unroll
            for (int rt = 0; rt < 2; ++rt)
              fa[rt][ctl] = __builtin_amdgcn_mfma_f32_16x16x32_bf16(a[rt], br[ctl], fa[rt][ctl], 0, 0, 0);
        }
        if (ch < 7) mfma1(nxt);
      }

      // ---- residual + bias + LN2
      float g4[4], bb4[4], b2v[4];
      #pragma unroll
      for (int ctl = 0; ctl < 4; ++ctl){
        int col = 64*wc + 16*ctl + li;
        g4[ctl] = ln2s[l*256 + col]; bb4[ctl] = ln2b[l*256 + col]; b2v[ctl] = b2[l*256 + col];
      }
      float s1v[2][4], s2v[2][4];
      #pragma unroll
      for (int rt = 0; rt < 2; ++rt)
        #pragma unroll
        for (int r = 0; r < 4; ++r){
          float t1 = 0.f, t2 = 0.f;
          #pragma unroll
          for (int ctl = 0; ctl < 4; ++ctl){
            float y = fa[rt][ctl][r] + xres[rt][ctl][r] + b2v[ctl];
            fa[rt][ctl][r] = y; t1 += y; t2 += y * y;
          }
          #pragma unroll
          for (int o = 1; o < 16; o <<= 1){ t1 += __shfl_xor(t1, o, 64); t2 += __shfl_xor(t2, o, 64); }
          s1v[rt][r] = t1; s2v[rt][r] = t2;
        }
      if (li == 0){
        #pragma unroll
        for (int rt = 0; rt < 2; ++rt)
          #pragma unroll
          for (int r = 0; r < 4; ++r){
            sStat[rbase + 16*rt + 4*lg + r][wc] = s1v[rt][r];
            sStat[rbase + 16*rt + 4*lg + r][4 + wc] = s2v[rt][r];
          }
      }
      SBAR();
      #pragma unroll
      for (int rt = 0; rt < 2; ++rt)
        #pragma unroll
        for (int r = 0; r < 4; ++r){
          int row = rbase + 16*rt + 4*lg + r;
          float su = sStat[row][0] + sStat[row][1] + sStat[row][2] + sStat[row][3];
          float sq = sStat[row][4] + sStat[row][5] + sStat[row][6] + sStat[row][7];
          float mean = su * (1.f / 256.f);
          float var = sq * (1.f / 256.f) - mean * mean;
          float rs = rsqrtf(var + 1e-5f);
          #pragma unroll
          for (int ctl = 0; ctl < 4; ++ctl){
            int col = 64*wc + 16*ctl + li;
            float nv = (fa[rt][ctl][r] - mean) * rs * g4[ctl] + bb4[ctl];
            xres[rt][ctl][r] = nv;
            sXb[xoff(row, col)] = (u16)f2bf(nv);
            if (l == 3 && outCLS && row == 0) outCLS[term * 256 + col] = nv;
          }
        }
      SBAR();
    }
  }
}

extern "C" void kernel_launch(void* const* d_in, const int* in_sizes, int n_in,
                              void* d_out, int out_size, void* d_ws, size_t ws_size,
                              hipStream_t stream)
{
  (void)in_sizes; (void)n_in; (void)out_size; (void)ws_size;
  const int* tokens_scope = (const int*)d_in[0];
  const int* tokens_hole  = (const int*)d_in[1];
  const void* pad_scope = d_in[2];
  const void* pad_hole  = d_in[3];
  const void* ref_scope = d_in[4];
  const void* ref_hole  = d_in[5];
  const int* scope_sort = (const int*)d_in[6];
  const int* scope_pos  = (const int*)d_in[7];
  const float* emb  = (const float*)d_in[8];
  const float* Wq   = (const float*)d_in[9];
  const float* Wk   = (const float*)d_in[10];
  const float* Wv   = (const float*)d_in[11];
  const float* Wo   = (const float*)d_in[12];
  const float* ln1s = (const float*)d_in[13];
  const float* ln1b = (const float*)d_in[14];
  const float* W1   = (const float*)d_in[15];
  const float* b1   = (const float*)d_in[16];
  const float* W2   = (const float*)d_in[17];
  const float* b2   = (const float*)d_in[18];
  const float* ln2s = (const float*)d_in[19];
  const float* ln2b = (const float*)d_in[20];

  char* p = (char*)d_ws;
  float* reprs  = (float*)p; p += (size_t)2048*256*4;
  float* encCLS = (float*)p; p += (size_t)2048*256*4;
  u16* WqF = (u16*)p; p += (size_t)4*256*256*2;
  u16* WkF = (u16*)p; p += (size_t)4*256*256*2;
  u16* WvF = (u16*)p; p += (size_t)4*256*256*2;
  u16* WoF = (u16*)p; p += (size_t)4*256*256*2;
  u16* W1F = (u16*)p; p += (size_t)4*256*1024*2;
  u16* W2F = (u16*)p; p += (size_t)4*256*1024*2;
  u16* embB = (u16*)p; p += (size_t)3*2048*256*2;
  int* lists = (int*)p; p += (size_t)4*2048*4;
  int* counts = (int*)p; p += 64;
  int* flag = (int*)p; p += 16;

  hipLaunchKernelGGL(detect_bool_k, dim3(1), dim3(64), 0, stream, pad_scope, flag, counts);
  hipLaunchKernelGGL(prep_k, dim3(20480), dim3(256), 0, stream,
                     emb, embB, Wq, Wk, Wv, Wo, W1, W2,
                     WqF, WkF, WvF, WoF, W1F, W2F, scope_pos, reprs);
  hipLaunchKernelGGL(compact_k, dim3(8), dim3(256), 0, stream, scope_sort, lists, counts);

  for (int r = 0; r < 4; ++r){
    hipLaunchKernelGGL(encode_k, dim3(2048), dim3(512), 0, stream,
      tokens_scope, pad_scope, ref_scope, flag, reprs, embB,
      WqF, WkF, WvF, WoF, W1F, b1, W2F, b2, ln1s, ln1b, ln2s, ln2b,
      lists + (size_t)r*2048, counts + r, encCLS);
    hipLaunchKernelGGL(update_k, dim3(2048), dim3(256), 0, stream,
      lists + (size_t)r*2048, counts + r, encCLS, reprs);
  }
  hipLaunchKernelGGL(encode_k, dim3(512), dim3(512), 0, stream,
      tokens_hole, pad_hole, ref_hole, flag, reprs, embB,
      WqF, WkF, WvF, WoF, W1F, b1, W2F, b2, ln1s, ln1b, ln2s, ln2b,
      (const int*)nullptr, (const int*)nullptr, (float*)d_out + (size_t)2048*256);
  hipLaunchKernelGGL(writeout_k, dim3(2048), dim3(256), 0, stream, reprs, (float*)d_out);
}